// Round 8
// baseline (455.919 us; speedup 1.0000x reference)
//
#include <hip/hip_runtime.h>
#include <hip/hip_bf16.h>
#include <hip/hip_cooperative_groups.h>

namespace cg = cooperative_groups;

#define BB 8
#define NN 1024
#define IN_DIM 256
#define OUT_DIM 256
#define NH 4
#define HD 64
#define TN 16            // query rows per attn tile
#define PSTRIDE 1032     // p_lds row stride in bf16 elems (2-way bank alias = free; 16B-aligned rows)

typedef __attribute__((ext_vector_type(8))) short short8;     // 8 x bf16 MFMA frag
typedef __attribute__((ext_vector_type(4))) short short4e;    // 4 x bf16 packed store
typedef __attribute__((ext_vector_type(4))) float floatx4;
typedef __attribute__((ext_vector_type(4))) int intx4;

// One cooperative kernel, grid = 512 blocks x 256 threads (2 blocks/CU co-resident).
// S0 prep (40 blocks) | S1 Wh GEMM (512x16 rows) | S2 attn (4 tiles/block) | S3 proj+LN.
__global__ __launch_bounds__(256) void fused_gat_kernel(
    const float* __restrict__ h, const int* __restrict__ adj,
    const float* __restrict__ W, const float* __restrict__ a1, const float* __restrict__ a2,
    const float* __restrict__ proj_w, const float* __restrict__ proj_b,
    const float* __restrict__ gamma, const float* __restrict__ beta,
    float* __restrict__ out,
    __hip_bfloat16* __restrict__ WTb,   // [256 o][256 k]
    __hip_bfloat16* __restrict__ pwb,   // [256 o][256 k]
    __hip_bfloat16* __restrict__ wab,   // [16][256]
    __hip_bfloat16* __restrict__ WhT,   // [B*H][HD][NN]
    float* __restrict__ si, float* __restrict__ sj,
    __hip_bfloat16* __restrict__ hmb)   // [B*N][256]
{
    cg::grid_group grid = cg::this_grid();
    int blk = blockIdx.x, t = threadIdx.x;
    int w = t >> 6, l = t & 63;
    int rl = l & 15, q = l >> 4;

    __shared__ __align__(16) __hip_bfloat16 p_lds[TN * PSTRIDE];
    __shared__ float rinv[TN];
    __shared__ float red[2][4][16];

    // ---------------- S0: prep ----------------
    if (blk < 16) {
        int o = blk * 16 + (t >> 4);
        int hh = o >> 6, d = o & 63;
        #pragma unroll
        for (int kk = 0; kk < 16; ++kk) {
            int k = (t & 15) + 16 * kk;
            WTb[(size_t)o * 256 + k] = __float2bfloat16(W[((size_t)hh * 256 + k) * 64 + d]);
        }
    } else if (blk < 32) {
        size_t base = (size_t)(blk - 16) * 4096 + t * 16;
        #pragma unroll
        for (int k = 0; k < 16; k += 4) {
            floatx4 v = *(const floatx4*)(proj_w + base + k);
            alignas(8) __hip_bfloat16 tmp[4];
            #pragma unroll
            for (int j = 0; j < 4; ++j) tmp[j] = __float2bfloat16(v[j]);
            *(short4e*)(pwb + base + k) = *(const short4e*)tmp;
        }
    } else if (blk < 40) {
        int r = blk - 32;                 // 0..7
        int hh = r & 3;
        const float* av = (r < 4 ? a1 : a2) + hh * HD;
        const float* wrow = W + ((size_t)hh * 256 + t) * HD;
        float s = 0.f;
        #pragma unroll 8
        for (int d = 0; d < HD; ++d) s += wrow[d] * av[d];
        wab[(size_t)r * 256 + t] = __float2bfloat16(s);
        wab[(size_t)(r + 8) * 256 + t] = __float2bfloat16(0.f);
    }
    __threadfence();
    grid.sync();

    // ---------------- S1: Wh GEMM (+ si/sj extra tile) ----------------
    {
        int r0 = blk * 16;
        short8 af[8];
        const float* Arow = h + (size_t)(r0 + rl) * 256 + q * 8;
        #pragma unroll
        for (int k0 = 0; k0 < 8; ++k0) {
            floatx4 v0 = *(const floatx4*)(Arow + k0 * 32);
            floatx4 v1 = *(const floatx4*)(Arow + k0 * 32 + 4);
            short8 a;
            #pragma unroll
            for (int j = 0; j < 4; ++j) {
                a[j]     = (short)(__bfloat16_as_ushort(__float2bfloat16(v0[j])));
                a[j + 4] = (short)(__bfloat16_as_ushort(__float2bfloat16(v1[j])));
            }
            af[k0] = a;
        }

        int bb = r0 >> 10;
        int n0 = (r0 & 1023) + q * 4;

        #pragma unroll
        for (int j = 0; j < 4; ++j) {
            int ct = w + j * 4;
            const __hip_bfloat16* Brow = WTb + (size_t)(ct * 16 + rl) * 256 + q * 8;
            floatx4 acc = {0.f, 0.f, 0.f, 0.f};
            #pragma unroll
            for (int k0 = 0; k0 < 8; ++k0) {
                short8 bf = *(const short8*)(Brow + k0 * 32);
                acc = __builtin_amdgcn_mfma_f32_16x16x32_bf16(af[k0], bf, acc, 0, 0, 0);
            }
            int o = ct * 16 + rl;
            int hh = o >> 6, d = o & 63;
            alignas(8) __hip_bfloat16 tmp[4];
            #pragma unroll
            for (int i = 0; i < 4; ++i) tmp[i] = __float2bfloat16(acc[i]);
            *(short4e*)(WhT + ((size_t)(bb * NH + hh) * HD + d) * NN + n0) = *(const short4e*)tmp;
        }

        if (w == 0) {
            const __hip_bfloat16* Brow = wab + (size_t)rl * 256 + q * 8;
            floatx4 acc = {0.f, 0.f, 0.f, 0.f};
            #pragma unroll
            for (int k0 = 0; k0 < 8; ++k0) {
                short8 bf = *(const short8*)(Brow + k0 * 32);
                acc = __builtin_amdgcn_mfma_f32_16x16x32_bf16(af[k0], bf, acc, 0, 0, 0);
            }
            if (rl < 8) {
                int hh = rl & 3;
                float* dst = (rl < 4 ? si : sj) + ((size_t)(bb * NH + hh)) * NN + n0;
                *(floatx4*)dst = acc;
            }
        }
    }
    __threadfence();
    grid.sync();

    // ---------------- S2: attn, 4 tiles per block ----------------
    for (int it = 0; it < 4; ++it) {
        __syncthreads();   // protect p_lds reuse across iterations
        int bx = blk * 4 + it;
        int bh = bx >> 6;
        int n0 = (bx & 63) * TN;

        int r = t >> 4;
        int c = t & 15;
        int n = n0 + r;
        float sii = si[(size_t)bh * NN + n];
        const float* sjr = sj + (size_t)bh * NN;
        const int* adjr = adj + (size_t)n * NN;

        float lsum = 0.f;
        #pragma unroll 4
        for (int jj = 0; jj < 16; ++jj) {
            int m = jj * 64 + c * 4;
            floatx4 s4 = *(const floatx4*)(sjr + m);
            intx4 a4 = *(const intx4*)(adjr + m);
            alignas(8) __hip_bfloat16 tmp[4];
            #pragma unroll
            for (int k = 0; k < 4; ++k) {
                float x = sii + s4[k];
                x = x > 0.f ? x : 0.2f * x;
                x = (a4[k] == 0) ? -1e9f : x;
                float pv = __expf(x);
                lsum += pv;
                tmp[k] = __float2bfloat16(pv);
            }
            *(short4e*)(p_lds + (size_t)r * PSTRIDE + m) = *(const short4e*)tmp;
        }
        #pragma unroll
        for (int off = 1; off < 16; off <<= 1) lsum += __shfl_xor(lsum, off, 64);
        if (c == 0) rinv[r] = 1.f / lsum;
        __syncthreads();

        int d0 = w * 16;
        const __hip_bfloat16* Bbase = WhT + ((size_t)bh * HD + d0 + rl) * NN + q * 8;
        const __hip_bfloat16* Abase = p_lds + (size_t)rl * PSTRIDE + q * 8;

        floatx4 acc = {0.f, 0.f, 0.f, 0.f};
        #pragma unroll 4
        for (int k0 = 0; k0 < NN; k0 += 32) {
            short8 af = *(const short8*)(Abase + k0);
            short8 bf = *(const short8*)(Bbase + k0);
            acc = __builtin_amdgcn_mfma_f32_16x16x32_bf16(af, bf, acc, 0, 0, 0);
        }

        int b = bh >> 2, hhh = bh & 3;
        #pragma unroll
        for (int i = 0; i < 4; ++i) {
            int nr = q * 4 + i;
            float v = acc[i] * rinv[nr];
            hmb[((size_t)(b * NN) + n0 + nr) * OUT_DIM + hhh * HD + d0 + rl] = __float2bfloat16(v);
        }
    }
    __threadfence();
    grid.sync();

    // ---------------- S3: proj + bias + residual + LayerNorm ----------------
    {
        int r0 = blk * 16;
        short8 af[8];
        const __hip_bfloat16* Arow = hmb + (size_t)(r0 + rl) * 256 + q * 8;
        #pragma unroll
        for (int k0 = 0; k0 < 8; ++k0) af[k0] = *(const short8*)(Arow + k0 * 32);

        floatx4 acc[4];
        #pragma unroll
        for (int j = 0; j < 4; ++j) {
            int ct = w + j * 4;
            const __hip_bfloat16* Brow = pwb + (size_t)(ct * 16 + rl) * 256 + q * 8;
            floatx4 a = {0.f, 0.f, 0.f, 0.f};
            #pragma unroll
            for (int k0 = 0; k0 < 8; ++k0) {
                short8 bf = *(const short8*)(Brow + k0 * 32);
                a = __builtin_amdgcn_mfma_f32_16x16x32_bf16(af[k0], bf, a, 0, 0, 0);
            }
            acc[j] = a;
        }

        float ps[4] = {0.f, 0.f, 0.f, 0.f};
        #pragma unroll
        for (int j = 0; j < 4; ++j) {
            int col = (w + j * 4) * 16 + rl;
            float pb = proj_b[col];
            #pragma unroll
            for (int i = 0; i < 4; ++i) {
                float v = acc[j][i] + pb + h[(size_t)(r0 + q * 4 + i) * 256 + col];
                acc[j][i] = v;
                ps[i] += v;
            }
        }
        #pragma unroll
        for (int i = 0; i < 4; ++i) {
            float s = ps[i];
            #pragma unroll
            for (int off = 1; off < 16; off <<= 1) s += __shfl_xor(s, off, 64);
            ps[i] = s;
        }
        __syncthreads();   // red[] reuse vs S2's rinv/red lifetimes
        if (rl == 0) {
            for (int i = 0; i < 4; ++i) red[0][w][q * 4 + i] = ps[i];
        }
        __syncthreads();
        float mu[4];
        #pragma unroll
        for (int i = 0; i < 4; ++i) {
            int row = q * 4 + i;
            mu[i] = (red[0][0][row] + red[0][1][row] + red[0][2][row] + red[0][3][row]) * (1.f / 256.f);
        }

        float vs[4] = {0.f, 0.f, 0.f, 0.f};
        #pragma unroll
        for (int j = 0; j < 4; ++j) {
            #pragma unroll
            for (int i = 0; i < 4; ++i) { float cv = acc[j][i] - mu[i]; vs[i] += cv * cv; }
        }
        #pragma unroll
        for (int i = 0; i < 4; ++i) {
            float s = vs[i];
            #pragma unroll
            for (int off = 1; off < 16; off <<= 1) s += __shfl_xor(s, off, 64);
            vs[i] = s;
        }
        if (rl == 0) {
            for (int i = 0; i < 4; ++i) red[1][w][q * 4 + i] = vs[i];
        }
        __syncthreads();
        float rs[4];
        #pragma unroll
        for (int i = 0; i < 4; ++i) {
            int row = q * 4 + i;
            float var = (red[1][0][row] + red[1][1][row] + red[1][2][row] + red[1][3][row]) * (1.f / 256.f);
            rs[i] = rsqrtf(var + 1e-5f);
        }

        #pragma unroll
        for (int j = 0; j < 4; ++j) {
            int col = (w + j * 4) * 16 + rl;
            float g = gamma[col], be = beta[col];
            #pragma unroll
            for (int i = 0; i < 4; ++i)
                out[(size_t)(r0 + q * 4 + i) * 256 + col] = (acc[j][i] - mu[i]) * rs[i] * g + be;
        }
    }
}

extern "C" void kernel_launch(void* const* d_in, const int* in_sizes, int n_in,
                              void* d_out, int out_size, void* d_ws, size_t ws_size,
                              hipStream_t stream) {
    const float* h      = (const float*)d_in[0];
    const int*   adj    = (const int*)d_in[1];
    const float* W      = (const float*)d_in[2];
    const float* a1     = (const float*)d_in[3];
    const float* a2     = (const float*)d_in[4];
    const float* proj_w = (const float*)d_in[5];
    const float* proj_b = (const float*)d_in[6];
    const float* gamma  = (const float*)d_in[7];
    const float* beta   = (const float*)d_in[8];
    float* out = (float*)d_out;

    char* ws = (char*)d_ws;
    __hip_bfloat16* WhT = (__hip_bfloat16*)ws;                    ws += (size_t)BB*NH*HD*NN*2;    // 4 MB
    __hip_bfloat16* hmb = (__hip_bfloat16*)ws;                    ws += (size_t)BB*NN*OUT_DIM*2;  // 4 MB
    __hip_bfloat16* WTb = (__hip_bfloat16*)ws;                    ws += 256*256*2;                // 128 KB
    __hip_bfloat16* pwb = (__hip_bfloat16*)ws;                    ws += 256*256*2;                // 128 KB
    __hip_bfloat16* wab = (__hip_bfloat16*)ws;                    ws += 16*256*2;                 // 8 KB
    float* si = (float*)ws;                                       ws += (size_t)BB*NH*NN*4;       // 128 KB
    float* sj = (float*)ws;

    void* args[] = { (void*)&h, (void*)&adj, (void*)&W, (void*)&a1, (void*)&a2,
                     (void*)&proj_w, (void*)&proj_b, (void*)&gamma, (void*)&beta,
                     (void*)&out, (void*)&WTb, (void*)&pwb, (void*)&wab,
                     (void*)&WhT, (void*)&si, (void*)&sj, (void*)&hmb };
    hipLaunchCooperativeKernel((void*)fused_gat_kernel, dim3(512), dim3(256), args, 0, stream);
}

// Round 9
// 141.973 us; speedup vs baseline: 3.2113x; 3.2113x over previous
//
#include <hip/hip_runtime.h>
#include <hip/hip_bf16.h>

#define BB 8
#define NN 1024
#define IN_DIM 256
#define OUT_DIM 256
#define NH 4
#define HD 64
#define TN 16            // query rows per attn block
#define TM 128           // key (m) tile per attn iteration
#define PSTR 136         // p_lds row stride in bf16 elems (128 + 8; 16B-aligned rows, balanced banks)

typedef __attribute__((ext_vector_type(8))) short short8;     // 8 x bf16 MFMA frag
typedef __attribute__((ext_vector_type(4))) short short4e;    // 4 x bf16 packed store
typedef __attribute__((ext_vector_type(4))) float floatx4;
typedef __attribute__((ext_vector_type(4))) int intx4;

// ---------------- Kernel 0: prep — WTb / pwb bf16, wab score vectors, adj bitmask ----------------
// grid = 16 (W transpose) + 16 (proj_w cast) + 8 (wab rows) + 128 (bitmask) = 168 blocks
__global__ __launch_bounds__(256) void prep_kernel(
    const float* __restrict__ W,
    const float* __restrict__ a1, const float* __restrict__ a2,
    const float* __restrict__ proj_w, const int* __restrict__ adj,
    __hip_bfloat16* __restrict__ WTb,     // [256 o][256 k], o = hh*64+d
    __hip_bfloat16* __restrict__ pwb,     // [256 o][256 k]
    __hip_bfloat16* __restrict__ wab,     // [16][256]
    unsigned* __restrict__ adjm)          // [1024][32] bitmask
{
    int blk = blockIdx.x, t = threadIdx.x;
    if (blk < 16) {
        int o = blk * 16 + (t >> 4);
        int hh = o >> 6, d = o & 63;
        #pragma unroll
        for (int kk = 0; kk < 16; ++kk) {
            int k = (t & 15) + 16 * kk;
            WTb[(size_t)o * 256 + k] = __float2bfloat16(W[((size_t)hh * 256 + k) * 64 + d]);
        }
    } else if (blk < 32) {
        size_t base = (size_t)(blk - 16) * 4096 + t * 16;
        #pragma unroll
        for (int k = 0; k < 16; k += 4) {
            floatx4 v = *(const floatx4*)(proj_w + base + k);
            alignas(8) __hip_bfloat16 tmp[4];
            #pragma unroll
            for (int j = 0; j < 4; ++j) tmp[j] = __float2bfloat16(v[j]);
            *(short4e*)(pwb + base + k) = *(const short4e*)tmp;
        }
    } else if (blk < 40) {
        int r = blk - 32;                 // 0..7
        int hh = r & 3;
        const float* av = (r < 4 ? a1 : a2) + hh * HD;
        const float* wrow = W + ((size_t)hh * 256 + t) * HD;
        float s = 0.f;
        #pragma unroll 8
        for (int d = 0; d < HD; ++d) s += wrow[d] * av[d];
        wab[(size_t)r * 256 + t] = __float2bfloat16(s);
        wab[(size_t)(r + 8) * 256 + t] = __float2bfloat16(0.f);
    } else {
        int bp = blk - 40;                // 0..127, 8 rows each
        int n = bp * 8 + (t >> 5);
        int wd = t & 31;
        const int* arow = adj + (size_t)n * NN + wd * 32;
        unsigned bits = 0;
        #pragma unroll
        for (int j4 = 0; j4 < 8; ++j4) {
            intx4 v = *(const intx4*)(arow + j4 * 4);
            #pragma unroll
            for (int j = 0; j < 4; ++j) if (v[j] != 0) bits |= (1u << (j4 * 4 + j));
        }
        adjm[(size_t)n * 32 + wd] = bits;
    }
}

// ---------------- Kernel 1: Wh via MFMA (f32 h read + inline bf16 cast); si/sj as extra cols ----------------
// grid = 512 blocks, 256 threads = 4 waves; wave w takes col-tiles w+4j.
__global__ __launch_bounds__(256) void wh_mfma_kernel(
    const float* __restrict__ h,
    const __hip_bfloat16* __restrict__ WTb,
    const __hip_bfloat16* __restrict__ wab,
    __hip_bfloat16* __restrict__ WhT,    // [B*H][HD][NN]
    float* __restrict__ si, float* __restrict__ sj)
{
    int t = threadIdx.x;
    int w = t >> 6, l = t & 63;
    int rl = l & 15, q = l >> 4;
    int r0 = blockIdx.x * 16;

    short8 af[8];
    const float* Arow = h + (size_t)(r0 + rl) * 256 + q * 8;
    #pragma unroll
    for (int k0 = 0; k0 < 8; ++k0) {
        floatx4 v0 = *(const floatx4*)(Arow + k0 * 32);
        floatx4 v1 = *(const floatx4*)(Arow + k0 * 32 + 4);
        short8 a;
        #pragma unroll
        for (int j = 0; j < 4; ++j) {
            a[j]     = (short)(__bfloat16_as_ushort(__float2bfloat16(v0[j])));
            a[j + 4] = (short)(__bfloat16_as_ushort(__float2bfloat16(v1[j])));
        }
        af[k0] = a;
    }

    int bb = r0 >> 10;
    int n0 = (r0 & 1023) + q * 4;

    #pragma unroll
    for (int j = 0; j < 4; ++j) {
        int ct = w + j * 4;
        const __hip_bfloat16* Brow = WTb + (size_t)(ct * 16 + rl) * 256 + q * 8;
        floatx4 acc = {0.f, 0.f, 0.f, 0.f};
        #pragma unroll
        for (int k0 = 0; k0 < 8; ++k0) {
            short8 bf = *(const short8*)(Brow + k0 * 32);
            acc = __builtin_amdgcn_mfma_f32_16x16x32_bf16(af[k0], bf, acc, 0, 0, 0);
        }
        int o = ct * 16 + rl;
        int hh = o >> 6, d = o & 63;
        alignas(8) __hip_bfloat16 tmp[4];
        #pragma unroll
        for (int i = 0; i < 4; ++i) tmp[i] = __float2bfloat16(acc[i]);
        *(short4e*)(WhT + ((size_t)(bb * NH + hh) * HD + d) * NN + n0) = *(const short4e*)tmp;
    }

    if (w == 0) {
        const __hip_bfloat16* Brow = wab + (size_t)rl * 256 + q * 8;
        floatx4 acc = {0.f, 0.f, 0.f, 0.f};
        #pragma unroll
        for (int k0 = 0; k0 < 8; ++k0) {
            short8 bf = *(const short8*)(Brow + k0 * 32);
            acc = __builtin_amdgcn_mfma_f32_16x16x32_bf16(af[k0], bf, acc, 0, 0, 0);
        }
        if (rl < 8) {
            int hh = rl & 3;
            float* dst = (rl < 4 ? si : sj) + ((size_t)(bb * NH + hh)) * NN + n0;
            *(floatx4*)dst = acc;
        }
    }
}

// ---------------- Kernel 2: m-tiled masked softmax + MFMA-accumulated alpha @ Wh ----------------
// grid = B*H*(N/16) = 2048 blocks, 256 threads. LDS ~4.5 KB -> full occupancy.
__global__ __launch_bounds__(256) void attn_kernel(
    const unsigned* __restrict__ adjm,
    const __hip_bfloat16* __restrict__ WhT,
    const float* __restrict__ si,
    const float* __restrict__ sj,
    __hip_bfloat16* __restrict__ hmb)   // [B*N][256] concat-head
{
    int bx = blockIdx.x;
    int bh = bx >> 6;
    int n0 = (bx & 63) * TN;
    int t = threadIdx.x;

    __shared__ __align__(16) __hip_bfloat16 p_lds[TN * PSTR];
    __shared__ float rinv[TN];

    // score-role indices
    int r = t >> 4, c = t & 15;
    int n = n0 + r;
    float sii = si[(size_t)bh * NN + n];
    const float* sjr = sj + (size_t)bh * NN;
    const unsigned* amrow = adjm + (size_t)n * 32;

    // MFMA-role indices
    int w = t >> 6, l = t & 63;
    int rl = l & 15, q = l >> 4;
    int d0 = w * 16;
    const __hip_bfloat16* Bb = WhT + ((size_t)bh * HD + d0 + rl) * NN + q * 8;
    const __hip_bfloat16* Ab = p_lds + (size_t)rl * PSTR + q * 8;

    float lsum = 0.f;
    floatx4 acc = {0.f, 0.f, 0.f, 0.f};

    for (int m0 = 0; m0 < NN; m0 += TM) {
        floatx4 s0 = *(const floatx4*)(sjr + m0 + c * 8);
        floatx4 s1 = *(const floatx4*)(sjr + m0 + c * 8 + 4);
        unsigned wv = amrow[(m0 >> 5) + (c >> 2)];
        unsigned sh = (c & 3) * 8;
        alignas(16) __hip_bfloat16 tmp[8];
        #pragma unroll
        for (int k = 0; k < 8; ++k) {
            float x = sii + (k < 4 ? s0[k] : s1[k - 4]);
            x = x > 0.f ? x : 0.2f * x;                    // leaky_relu 0.2
            x = ((wv >> (sh + k)) & 1u) ? x : -1e9f;       // mask
            float pv = __expf(x);
            lsum += pv;
            tmp[k] = __float2bfloat16(pv);
        }
        *(short8*)(p_lds + (size_t)r * PSTR + c * 8) = *(const short8*)tmp;
        __syncthreads();
        #pragma unroll
        for (int ks = 0; ks < 4; ++ks) {
            short8 af = *(const short8*)(Ab + ks * 32);
            short8 bf = *(const short8*)(Bb + m0 + ks * 32);
            acc = __builtin_amdgcn_mfma_f32_16x16x32_bf16(af, bf, acc, 0, 0, 0);
        }
        __syncthreads();
    }

    #pragma unroll
    for (int off = 1; off < 16; off <<= 1) lsum += __shfl_xor(lsum, off, 64);
    if (c == 0) rinv[r] = 1.f / lsum;
    __syncthreads();

    int b = bh >> 2, hhh = bh & 3;
    #pragma unroll
    for (int i = 0; i < 4; ++i) {
        int nr = q * 4 + i;
        float v = acc[i] * rinv[nr];
        hmb[((size_t)(b * NN) + n0 + nr) * OUT_DIM + hhh * HD + d0 + rl] = __float2bfloat16(v);
    }
}

// ---------------- Kernel 3: proj via MFMA + bias + residual + LayerNorm ----------------
// grid = 512 blocks, 256 threads = 4 waves; wave w takes col-tiles w+4j.
__global__ __launch_bounds__(256) void proj_ln_kernel(
    const __hip_bfloat16* __restrict__ hmb,
    const float* __restrict__ h,
    const __hip_bfloat16* __restrict__ pwb,
    const float* __restrict__ proj_b,
    const float* __restrict__ gamma,
    const float* __restrict__ beta,
    float* __restrict__ out)
{
    int t = threadIdx.x;
    int w = t >> 6, l = t & 63;
    int rl = l & 15, q = l >> 4;
    int r0 = blockIdx.x * 16;

    __shared__ float red[2][4][16];

    short8 af[8];
    const __hip_bfloat16* Arow = hmb + (size_t)(r0 + rl) * 256 + q * 8;
    #pragma unroll
    for (int k0 = 0; k0 < 8; ++k0) af[k0] = *(const short8*)(Arow + k0 * 32);

    floatx4 acc[4];
    #pragma unroll
    for (int j = 0; j < 4; ++j) {
        int ct = w + j * 4;
        const __hip_bfloat16* Brow = pwb + (size_t)(ct * 16 + rl) * 256 + q * 8;
        floatx4 a = {0.f, 0.f, 0.f, 0.f};
        #pragma unroll
        for (int k0 = 0; k0 < 8; ++k0) {
            short8 bf = *(const short8*)(Brow + k0 * 32);
            a = __builtin_amdgcn_mfma_f32_16x16x32_bf16(af[k0], bf, a, 0, 0, 0);
        }
        acc[j] = a;
    }

    float ps[4] = {0.f, 0.f, 0.f, 0.f};
    #pragma unroll
    for (int j = 0; j < 4; ++j) {
        int col = (w + j * 4) * 16 + rl;
        float pb = proj_b[col];
        #pragma unroll
        for (int i = 0; i < 4; ++i) {
            float v = acc[j][i] + pb + h[(size_t)(r0 + q * 4 + i) * 256 + col];
            acc[j][i] = v;
            ps[i] += v;
        }
    }
    #pragma unroll
    for (int i = 0; i < 4; ++i) {
        float s = ps[i];
        #pragma unroll
        for (int off = 1; off < 16; off <<= 1) s += __shfl_xor(s, off, 64);
        ps[i] = s;
    }
    if (rl == 0) {
        for (int i = 0; i < 4; ++i) red[0][w][q * 4 + i] = ps[i];
    }
    __syncthreads();
    float mu[4];
    #pragma unroll
    for (int i = 0; i < 4; ++i) {
        int row = q * 4 + i;
        mu[i] = (red[0][0][row] + red[0][1][row] + red[0][2][row] + red[0][3][row]) * (1.f / 256.f);
    }

    float vs[4] = {0.f, 0.f, 0.f, 0.f};
    #pragma unroll
    for (int j = 0; j < 4; ++j) {
        #pragma unroll
        for (int i = 0; i < 4; ++i) { float cv = acc[j][i] - mu[i]; vs[i] += cv * cv; }
    }
    #pragma unroll
    for (int i = 0; i < 4; ++i) {
        float s = vs[i];
        #pragma unroll
        for (int off = 1; off < 16; off <<= 1) s += __shfl_xor(s, off, 64);
        vs[i] = s;
    }
    if (rl == 0) {
        for (int i = 0; i < 4; ++i) red[1][w][q * 4 + i] = vs[i];
    }
    __syncthreads();
    float rs[4];
    #pragma unroll
    for (int i = 0; i < 4; ++i) {
        int row = q * 4 + i;
        float var = (red[1][0][row] + red[1][1][row] + red[1][2][row] + red[1][3][row]) * (1.f / 256.f);
        rs[i] = rsqrtf(var + 1e-5f);
    }

    #pragma unroll
    for (int j = 0; j < 4; ++j) {
        int col = (w + j * 4) * 16 + rl;
        float g = gamma[col], be = beta[col];
        #pragma unroll
        for (int i = 0; i < 4; ++i)
            out[(size_t)(r0 + q * 4 + i) * 256 + col] = (acc[j][i] - mu[i]) * rs[i] * g + be;
    }
}

extern "C" void kernel_launch(void* const* d_in, const int* in_sizes, int n_in,
                              void* d_out, int out_size, void* d_ws, size_t ws_size,
                              hipStream_t stream) {
    const float* h      = (const float*)d_in[0];
    const int*   adj    = (const int*)d_in[1];
    const float* W      = (const float*)d_in[2];
    const float* a1     = (const float*)d_in[3];
    const float* a2     = (const float*)d_in[4];
    const float* proj_w = (const float*)d_in[5];
    const float* proj_b = (const float*)d_in[6];
    const float* gamma  = (const float*)d_in[7];
    const float* beta   = (const float*)d_in[8];
    float* out = (float*)d_out;

    char* ws = (char*)d_ws;
    __hip_bfloat16* WhT = (__hip_bfloat16*)ws;                    ws += (size_t)BB*NH*HD*NN*2;    // 4 MB
    __hip_bfloat16* hmb = (__hip_bfloat16*)ws;                    ws += (size_t)BB*NN*OUT_DIM*2;  // 4 MB
    __hip_bfloat16* WTb = (__hip_bfloat16*)ws;                    ws += 256*256*2;                // 128 KB
    __hip_bfloat16* pwb = (__hip_bfloat16*)ws;                    ws += 256*256*2;                // 128 KB
    __hip_bfloat16* wab = (__hip_bfloat16*)ws;                    ws += 16*256*2;                 // 8 KB
    float* si = (float*)ws;                                       ws += (size_t)BB*NH*NN*4;       // 128 KB
    float* sj = (float*)ws;                                       ws += (size_t)BB*NH*NN*4;       // 128 KB
    unsigned* adjm = (unsigned*)ws;                               ws += (size_t)NN*32*4;          // 128 KB

    prep_kernel<<<168, 256, 0, stream>>>(W, a1, a2, proj_w, adj, WTb, pwb, wab, adjm);
    wh_mfma_kernel<<<512, 256, 0, stream>>>(h, WTb, wab, WhT, si, sj);
    attn_kernel<<<BB * NH * (NN / TN), 256, 0, stream>>>(adjm, WhT, si, sj, hmb);
    proj_ln_kernel<<<512, 256, 0, stream>>>(hmb, h, pwb, proj_b, gamma, beta, out);
}